// Round 4
// baseline (269.481 us; speedup 1.0000x reference)
//
#include <hip/hip_runtime.h>
#include <hip/hip_bf16.h>
#include <math.h>

#define BB 16
#define CC 512
#define NH 8
#define HD 64
#define NN 1024   // H*W
#define THREEC 1536

// Q pre-scale: (1/sqrt(64)) * log2(e)  -> softmax via raw v_exp_f32 (2^x)
#define QSCALE 0.18033688f

typedef __attribute__((ext_vector_type(8))) short bf16x8;
typedef __attribute__((ext_vector_type(4))) float f32x4;
typedef __attribute__((ext_vector_type(16))) float f32x16;

#if __has_builtin(__builtin_amdgcn_exp2f)
#define EXP2F __builtin_amdgcn_exp2f
#else
#define EXP2F exp2f
#endif

// workspace byte offsets
#define XT_OFF 0u           // bf16 x^T [b][n][c]          (16.78 MB)
#define WQ_OFF 16777216u    // bf16 w_qkv [1536][512]      (1.57 MB)
#define WP_OFF 18350080u    // bf16 w_proj [512][512]      (0.52 MB)
#define QB_OFF 18874368u    // bf16 Q (scaled QSCALE) [bh][n][d]
#define KB_OFF 35651584u    // bf16 K [bh][n][d]
#define VT_OFF 52428800u    // bf16 V^T [bh][d][n]
#define AB_OFF 69206016u    // bf16 attn-out [b][n][c]
// end 85983232 (82 MiB)

static __device__ inline unsigned short f2bf(float f) {
  union { float f; unsigned u; } v; v.f = f;
  unsigned r = v.u + 0x7fffu + ((v.u >> 16) & 1u);
  return (unsigned short)(r >> 16);
}

// pack two f32 -> two bf16 in a u32 (lo = a, hi = b)
static __device__ inline unsigned pk2bf(float a, float b) {
#if defined(__AMDGCN__) && __has_builtin(__builtin_amdgcn_cvt_pk_bf16_f32)
  typedef __attribute__((ext_vector_type(2))) __bf16 bfp2;
  union { bfp2 v; unsigned u; } z;
  z.v = __builtin_amdgcn_cvt_pk_bf16_f32(a, b);
  return z.u;
#else
  return (unsigned)f2bf(a) | ((unsigned)f2bf(b) << 16);
#endif
}

static __device__ inline void gld_lds16(const unsigned short* g, unsigned short* l) {
  __builtin_amdgcn_global_load_lds(
      (const __attribute__((address_space(1))) unsigned int*)g,
      (__attribute__((address_space(3))) unsigned int*)l, 16, 0, 0);
}

// ---------------------------------------------------------------------------
// prep_w: convert w_qkv (786432) + w_proj (262144) fp32 -> bf16
// ---------------------------------------------------------------------------
__global__ __launch_bounds__(256) void prep_w(const float* __restrict__ wqkv,
                                              const float* __restrict__ wproj,
                                              unsigned short* __restrict__ dq,
                                              unsigned short* __restrict__ dp) {
  const size_t i8 = ((size_t)blockIdx.x * 256 + threadIdx.x) * 8;
  const float* src;
  unsigned short* dst;
  if (i8 < 786432u) { src = wqkv + i8; dst = dq + i8; }
  else              { src = wproj + (i8 - 786432u); dst = dp + (i8 - 786432u); }
  float4 a = *(const float4*)src;
  float4 b = *(const float4*)(src + 4);
  unsigned short pk[8] = {f2bf(a.x), f2bf(a.y), f2bf(a.z), f2bf(a.w),
                          f2bf(b.x), f2bf(b.y), f2bf(b.z), f2bf(b.w)};
  *(uint4*)dst = *(const uint4*)pk;
}

// ---------------------------------------------------------------------------
// prep_xT: x [b][c][n] fp32 -> xT [b][n][c] bf16. 64x64 LDS tile transpose.
// ---------------------------------------------------------------------------
__global__ __launch_bounds__(256) void prep_xT(const float* __restrict__ x,
                                               unsigned short* __restrict__ xT) {
  const int b  = blockIdx.z;
  const int c0 = blockIdx.y * 64;
  const int n0 = blockIdx.x * 64;
  __shared__ float tile[64][65];
  const int t  = threadIdx.x;
  const int cl = t >> 4, n4 = (t & 15) * 4;
#pragma unroll
  for (int r = 0; r < 4; ++r) {
    float4 v = *(const float4*)&x[((size_t)b * CC + c0 + cl + 16 * r) * NN + n0 + n4];
    *(float4*)&tile[cl + 16 * r][n4] = v;
  }
  __syncthreads();
  const int nl = t >> 4, c4 = (t & 15) * 4;
#pragma unroll
  for (int r = 0; r < 4; ++r) {
    ushort4 p;
    p.x = f2bf(tile[c4 + 0][nl + 16 * r]);
    p.y = f2bf(tile[c4 + 1][nl + 16 * r]);
    p.z = f2bf(tile[c4 + 2][nl + 16 * r]);
    p.w = f2bf(tile[c4 + 3][nl + 16 * r]);
    *(ushort4*)&xT[((size_t)b * NN + n0 + nl + 16 * r) * CC + c0 + c4] = p;
  }
}

// ---------------------------------------------------------------------------
// qkv_mfma: [1536x512] @ [512x1024] per batch, bf16 MFMA, 128x128 tile BK=64.
// ---------------------------------------------------------------------------
__global__ __launch_bounds__(256) void qkv_mfma(const unsigned short* __restrict__ wq,
                                                const unsigned short* __restrict__ xT,
                                                unsigned short* __restrict__ qb,
                                                unsigned short* __restrict__ kb_,
                                                unsigned short* __restrict__ vt) {
  const int b  = blockIdx.z;
  const int o0 = blockIdx.y * 128;
  const int n0 = blockIdx.x * 128;
  const int t  = threadIdx.x;
  const int w    = t >> 6;
  const int lane = t & 63;
  const int quad = lane >> 4;
  const int l16  = lane & 15;
  const int m_off = (w >> 1) * 64;
  const int n_off = (w & 1) * 64;

  __shared__ unsigned short sm[17408];
  unsigned short* As = sm;
  unsigned short* Bs = sm + 8192;

  const int which = o0 >> 9;       // 0=Q,1=K,2=V
  const bool vmode = (which == 2);

  const int srow = lane >> 3;
  const int ssw  = ((lane & 7) ^ srow) * 8;
  const unsigned short* gA = wq + (size_t)(o0 + 32 * w + srow) * CC + ssw;
  const unsigned short* gB = xT + ((size_t)b * NN + n0 + 32 * w + srow) * CC + ssw;

  f32x4 acc[4][4] = {};

  for (int c0 = 0; c0 < CC; c0 += 64) {
    __syncthreads();
#pragma unroll
    for (int L = 0; L < 4; ++L) {
      gld_lds16(gA + (size_t)(8 * L) * CC + c0, &As[(32 * w + 8 * L) * 64]);
      gld_lds16(gB + (size_t)(8 * L) * CC + c0, &Bs[(32 * w + 8 * L) * 64]);
    }
    __syncthreads();
    const unsigned short* Af = vmode ? Bs : As;
    const unsigned short* Bf = vmode ? As : Bs;
#pragma unroll
    for (int ks = 0; ks < 2; ++ks) {
      const int ph = ((ks * 4 + quad) ^ (l16 & 7)) * 8;
      bf16x8 af[4], bfr[4];
#pragma unroll
      for (int i = 0; i < 4; ++i) {
        af[i]  = *(const bf16x8*)&Af[(m_off + 16 * i + l16) * 64 + ph];
        bfr[i] = *(const bf16x8*)&Bf[(n_off + 16 * i + l16) * 64 + ph];
      }
#pragma unroll
      for (int i = 0; i < 4; ++i)
#pragma unroll
        for (int j = 0; j < 4; ++j)
          acc[i][j] = __builtin_amdgcn_mfma_f32_16x16x32_bf16(af[i], bfr[j], acc[i][j], 0, 0, 0);
    }
  }

  __syncthreads();
  const float sc = (which == 0) ? QSCALE : 1.0f;
#pragma unroll
  for (int i = 0; i < 4; ++i) {
#pragma unroll
    for (int j = 0; j < 4; ++j) {
      const int Drow = m_off + 16 * i + quad * 4;
      const int Dcol = n_off + 16 * j + l16;
      ushort4 p;
      p.x = f2bf(acc[i][j][0] * sc);
      p.y = f2bf(acc[i][j][1] * sc);
      p.z = f2bf(acc[i][j][2] * sc);
      p.w = f2bf(acc[i][j][3] * sc);
      *(ushort4*)&sm[Dcol * 136 + Drow] = p;
    }
  }
  __syncthreads();
  const int lrow = t >> 1;
  const int half = t & 1;
  const unsigned short* src = &sm[lrow * 136 + 64 * half];
  if (!vmode) {
    const int hh = ((o0 >> 6) & 7) + half;
    unsigned short* dst = (which == 0 ? qb : kb_) +
        ((size_t)(b * NH + hh) * NN + n0 + lrow) * HD;
#pragma unroll
    for (int i = 0; i < 8; ++i) *(uint4*)(dst + 8 * i) = *(const uint4*)(src + 8 * i);
  } else {
    const int hh = ((o0 + lrow) >> 6) & 7;
    const int d  = lrow & 63;
    unsigned short* dst = vt + ((size_t)(b * NH + hh) * HD + d) * NN + n0 + 64 * half;
#pragma unroll
    for (int i = 0; i < 8; ++i) *(uint4*)(dst + 8 * i) = *(const uint4*)(src + 8 * i);
  }
}

// ---------------------------------------------------------------------------
// attn_mfma v7: DIRECT-FROM-L2 streaming, zero barriers, zero main-loop LDS.
// Rationale (R3): v4/v5/v6 schedule permutations all landed 60-63us with
// identical SQ_LDS_BANK_CONFLICT (structural 4-way on every ds_read_b128)
// and no saturated pipe -> the LDS+barrier structure itself was the bound.
// K/V per bh = 256 KB, all 8 query-blocks of a bh on one XCD -> <=4MB/XCD
// working set, L2-resident (m169 precedent: dropping LDS staging at S=1024
// was +26%). Fragments are loaded global->reg directly with the SAME
// lane->element mapping the LDS reads produced (swizzle now unnecessary):
//   QK A-frag: K[bh][32s + rho(l31)][16c + 8hi .. +8]
//   PV A-frag: V^T[bh][32mt + l31][32s + 16g + 8hi .. +8]
// Waves run fully decoupled (epilogue LDS is wave-private; no syncthreads
// anywhere). Manual 1-iteration K prefetch skew; V issued a phase early.
// ---------------------------------------------------------------------------
__global__ __launch_bounds__(256, 4) void attn_mfma(const unsigned short* __restrict__ Qg,
                                                    const unsigned short* __restrict__ Kg,
                                                    const unsigned short* __restrict__ Vtg,
                                                    unsigned short* __restrict__ attnB) {
  const int bh = blockIdx.x;     // id % 8 == bh % 8 -> XCD affinity
  const int b  = bh >> 3;
  const int h  = bh & 7;
  const int n0 = blockIdx.y * 128;
  const int t  = threadIdx.x;
  const int w    = t >> 6;
  const int lane = t & 63;
  const int l31  = lane & 31;
  const int hi   = lane >> 5;

  __shared__ unsigned short sm[9216];   // epilogue only (wave-private)

  // Q B-fragments (whole kernel): B[n=query=l31][k=d=16c+8hi+j]
  const unsigned short* qrow = Qg + ((size_t)bh * NN + n0 + w * 32 + l31) * HD + hi * 8;
  bf16x8 qf[4];
#pragma unroll
  for (int c = 0; c < 4; ++c) qf[c] = *(const bf16x8*)(qrow + 16 * c);

  // K A-row permutation: rho(l) swaps bits 2 and 3
  const int krow = (l31 & ~12) | ((l31 & 4) << 1) | ((l31 & 8) >> 1);

  // per-lane global bases
  const unsigned short* Kl = Kg + ((size_t)bh * NN + krow) * HD + 8 * hi;
  const unsigned short* Vl = Vtg + ((size_t)bh * HD + l31) * NN + 8 * hi;

  const f32x16 fz = {};
  f32x16 oacc[2] = {};   // O^T: D[m=d][n=query]
  float lx = 0.f, ly = 0.f;

  // sub-block s = 0..31 covers keys [32s, 32s+32)
  auto LDK = [&](bf16x8* kf, int s) {
    const unsigned short* p = Kl + (size_t)s * 32 * HD;
#pragma unroll
    for (int c = 0; c < 4; ++c) kf[c] = *(const bf16x8*)(p + 16 * c);
  };
  auto LDV = [&](bf16x8* vf, int s) {
    const unsigned short* p = Vl + 32 * s;
#pragma unroll
    for (int g = 0; g < 2; ++g)
#pragma unroll
      for (int mt = 0; mt < 2; ++mt)
        vf[2 * g + mt] = *(const bf16x8*)(p + (size_t)mt * 32 * NN + 16 * g);
  };
  auto QK = [&](const bf16x8* kf) -> f32x16 {
    f32x16 st = __builtin_amdgcn_mfma_f32_32x32x16_bf16(kf[0], qf[0], fz, 0, 0, 0);
#pragma unroll
    for (int c = 1; c < 4; ++c)
      st = __builtin_amdgcn_mfma_f32_32x32x16_bf16(kf[c], qf[c], st, 0, 0, 0);
    return st;
  };
  auto SM = [&](const f32x16& st, unsigned* P) {
#pragma unroll
    for (int i = 0; i < 8; ++i) {
      float ea = EXP2F(st[2 * i]);
      float eb = EXP2F(st[2 * i + 1]);
      lx += ea; ly += eb;
      P[i] = pk2bf(ea, eb);
    }
  };
  auto PV = [&](const bf16x8* vf, const unsigned* P) {
#pragma unroll
    for (int g = 0; g < 2; ++g) {
      union { unsigned u[4]; bf16x8 v; } cv;
      cv.u[0] = P[4 * g + 0]; cv.u[1] = P[4 * g + 1];
      cv.u[2] = P[4 * g + 2]; cv.u[3] = P[4 * g + 3];
#pragma unroll
      for (int mt = 0; mt < 2; ++mt)
        oacc[mt] = __builtin_amdgcn_mfma_f32_32x32x16_bf16(vf[2 * g + mt], cv.v, oacc[mt], 0, 0, 0);
    }
  };

  bf16x8 kA[4], kB[4], vA[4], vB[4];
  unsigned P[8];

  LDK(kA, 0);
#pragma unroll 1
  for (int s = 0; s < 32; s += 2) {
    LDK(kB, s + 1);              // prefetch next sub-block's K
    LDV(vA, s);                  // V for this sub-block (hidden by QK+SM)
    __builtin_amdgcn_s_setprio(1);
    f32x16 st = QK(kA);
    __builtin_amdgcn_s_setprio(0);
    SM(st, P);
    __builtin_amdgcn_s_setprio(1);
    PV(vA, P);
    __builtin_amdgcn_s_setprio(0);

    if (s + 2 < 32) LDK(kA, s + 2);
    LDV(vB, s + 1);
    __builtin_amdgcn_s_setprio(1);
    f32x16 st2 = QK(kB);
    __builtin_amdgcn_s_setprio(0);
    SM(st2, P);
    __builtin_amdgcn_s_setprio(1);
    PV(vB, P);
    __builtin_amdgcn_s_setprio(0);
  }

  float lsum = lx + ly;
  lsum += __shfl_xor(lsum, 32);
  const float inv = 1.0f / lsum;

  // epilogue: wave-private LDS [query][d] (pitch 72), then 64B global writes.
  // No barrier needed: each wave reads only its own region (lgkmcnt orders).
  unsigned short* Es = sm + w * 2304;   // 32 * 72 shorts per wave
#pragma unroll
  for (int mt = 0; mt < 2; ++mt) {
#pragma unroll
    for (int rr = 0; rr < 4; ++rr) {
      const int d = 32 * mt + 8 * rr + 4 * hi;
      ushort4 p;
      p.x = f2bf(oacc[mt][4 * rr + 0] * inv);
      p.y = f2bf(oacc[mt][4 * rr + 1] * inv);
      p.z = f2bf(oacc[mt][4 * rr + 2] * inv);
      p.w = f2bf(oacc[mt][4 * rr + 3] * inv);
      *(ushort4*)&Es[l31 * 72 + d] = p;
    }
  }
  const int q    = lane >> 1;
  const int half = lane & 1;
  const unsigned short* src = &Es[q * 72 + 32 * half];
  unsigned short* gdst = attnB + ((size_t)b * NN + n0 + w * 32 + q) * CC + h * HD + 32 * half;
#pragma unroll
  for (int i = 0; i < 4; ++i) *(uint4*)(gdst + 8 * i) = *(const uint4*)(src + 8 * i);
}

// ---------------------------------------------------------------------------
// proj_mfma: out = w_proj @ attn + bias, bf16 MFMA, fp32 out [b][c][n].
// ---------------------------------------------------------------------------
__global__ __launch_bounds__(256) void proj_mfma(const unsigned short* __restrict__ wp,
                                                 const unsigned short* __restrict__ aB,
                                                 const float* __restrict__ bias,
                                                 float* __restrict__ out) {
  const int b  = blockIdx.z;
  const int o0 = blockIdx.y * 128;
  const int n0 = blockIdx.x * 128;
  const int t  = threadIdx.x;
  const int w    = t >> 6;
  const int lane = t & 63;
  const int quad = lane >> 4;
  const int l16  = lane & 15;
  const int m_off = (w >> 1) * 64;
  const int n_off = (w & 1) * 64;

  __shared__ unsigned short sm[16384];
  unsigned short* As = sm;
  unsigned short* Bs = sm + 8192;

  const int srow = lane >> 3;
  const int ssw  = ((lane & 7) ^ srow) * 8;
  const unsigned short* gA = wp + (size_t)(o0 + 32 * w + srow) * CC + ssw;
  const unsigned short* gB = aB + ((size_t)b * NN + n0 + 32 * w + srow) * CC + ssw;

  f32x4 acc[4][4] = {};

  for (int c0 = 0; c0 < CC; c0 += 64) {
    __syncthreads();
#pragma unroll
    for (int L = 0; L < 4; ++L) {
      gld_lds16(gA + (size_t)(8 * L) * CC + c0, &As[(32 * w + 8 * L) * 64]);
      gld_lds16(gB + (size_t)(8 * L) * CC + c0, &Bs[(32 * w + 8 * L) * 64]);
    }
    __syncthreads();
#pragma unroll
    for (int ks = 0; ks < 2; ++ks) {
      const int ph = ((ks * 4 + quad) ^ (l16 & 7)) * 8;
      bf16x8 af[4], bfr[4];
#pragma unroll
      for (int i = 0; i < 4; ++i) {
        af[i]  = *(const bf16x8*)&As[(m_off + 16 * i + l16) * 64 + ph];
        bfr[i] = *(const bf16x8*)&Bs[(n_off + 16 * i + l16) * 64 + ph];
      }
#pragma unroll
      for (int i = 0; i < 4; ++i)
#pragma unroll
        for (int j = 0; j < 4; ++j)
          acc[i][j] = __builtin_amdgcn_mfma_f32_16x16x32_bf16(af[i], bfr[j], acc[i][j], 0, 0, 0);
    }
  }

#pragma unroll
  for (int i = 0; i < 4; ++i) {
#pragma unroll
    for (int r = 0; r < 4; ++r) {
      const int o = o0 + m_off + 16 * i + quad * 4 + r;
      const float bv = bias[o];
      float* orow = out + ((size_t)b * CC + o) * NN + n0 + n_off;
#pragma unroll
      for (int j = 0; j < 4; ++j)
        orow[16 * j + l16] = acc[i][j][r] + bv;
    }
  }
}

// ---------------------------------------------------------------------------
extern "C" void kernel_launch(void* const* d_in, const int* in_sizes, int n_in,
                              void* d_out, int out_size, void* d_ws, size_t ws_size,
                              hipStream_t stream) {
  const float* x      = (const float*)d_in[0];
  const float* w_qkv  = (const float*)d_in[1];
  const float* w_proj = (const float*)d_in[2];
  const float* b_proj = (const float*)d_in[3];
  char* wsb  = (char*)d_ws;
  float* out = (float*)d_out;

  unsigned short* xT  = (unsigned short*)(wsb + XT_OFF);
  unsigned short* wq  = (unsigned short*)(wsb + WQ_OFF);
  unsigned short* wp  = (unsigned short*)(wsb + WP_OFF);
  unsigned short* qb  = (unsigned short*)(wsb + QB_OFF);
  unsigned short* kb_ = (unsigned short*)(wsb + KB_OFF);
  unsigned short* vt  = (unsigned short*)(wsb + VT_OFF);
  unsigned short* aB  = (unsigned short*)(wsb + AB_OFF);

  prep_w<<<512, 256, 0, stream>>>(w_qkv, w_proj, wq, wp);
  prep_xT<<<dim3(16, 8, BB), 256, 0, stream>>>(x, xT);
  qkv_mfma<<<dim3(8, 12, BB), 256, 0, stream>>>(wq, xT, qb, kb_, vt);
  attn_mfma<<<dim3(BB * NH, NN / 128), 256, 0, stream>>>(qb, kb_, vt, aB);
  proj_mfma<<<dim3(8, 4, BB), 256, 0, stream>>>(wp, aB, b_proj, out);
}

// Round 5
// 191.509 us; speedup vs baseline: 1.4071x; 1.4071x over previous
//
#include <hip/hip_runtime.h>
#include <hip/hip_bf16.h>
#include <math.h>

#define BB 16
#define CC 512
#define NH 8
#define HD 64
#define NN 1024   // H*W
#define THREEC 1536

// Q pre-scale: (1/sqrt(64)) * log2(e)  -> softmax via raw v_exp_f32 (2^x)
#define QSCALE 0.18033688f

typedef __attribute__((ext_vector_type(8))) short bf16x8;
typedef __attribute__((ext_vector_type(4))) float f32x4;
typedef __attribute__((ext_vector_type(16))) float f32x16;

#if __has_builtin(__builtin_amdgcn_exp2f)
#define EXP2F __builtin_amdgcn_exp2f
#else
#define EXP2F exp2f
#endif

// workspace byte offsets
#define XT_OFF 0u           // bf16 x^T [b][n][c]          (16.78 MB)
#define WQ_OFF 16777216u    // bf16 w_qkv [1536][512]      (1.57 MB)
#define WP_OFF 18350080u    // bf16 w_proj [512][512]      (0.52 MB)
#define QB_OFF 18874368u    // bf16 Q (scaled QSCALE) [bh][n][d]
#define KB_OFF 35651584u    // bf16 K [bh][n][d]
#define VT_OFF 52428800u    // bf16 V^T [bh][d][n]
#define AB_OFF 69206016u    // bf16 attn-out [b][n][c]
// end 85983232 (82 MiB)

static __device__ inline unsigned short f2bf(float f) {
  union { float f; unsigned u; } v; v.f = f;
  unsigned r = v.u + 0x7fffu + ((v.u >> 16) & 1u);
  return (unsigned short)(r >> 16);
}

// pack two f32 -> two bf16 in a u32 (lo = a, hi = b)
static __device__ inline unsigned pk2bf(float a, float b) {
#if defined(__AMDGCN__) && __has_builtin(__builtin_amdgcn_cvt_pk_bf16_f32)
  typedef __attribute__((ext_vector_type(2))) __bf16 bfp2;
  union { bfp2 v; unsigned u; } z;
  z.v = __builtin_amdgcn_cvt_pk_bf16_f32(a, b);
  return z.u;
#else
  return (unsigned)f2bf(a) | ((unsigned)f2bf(b) << 16);
#endif
}

static __device__ inline void gld_lds16(const unsigned short* g, unsigned short* l) {
  __builtin_amdgcn_global_load_lds(
      (const __attribute__((address_space(1))) unsigned int*)g,
      (__attribute__((address_space(3))) unsigned int*)l, 16, 0, 0);
}

// ---------------------------------------------------------------------------
// prep_w: convert w_qkv (786432) + w_proj (262144) fp32 -> bf16
// ---------------------------------------------------------------------------
__global__ __launch_bounds__(256) void prep_w(const float* __restrict__ wqkv,
                                              const float* __restrict__ wproj,
                                              unsigned short* __restrict__ dq,
                                              unsigned short* __restrict__ dp) {
  const size_t i8 = ((size_t)blockIdx.x * 256 + threadIdx.x) * 8;
  const float* src;
  unsigned short* dst;
  if (i8 < 786432u) { src = wqkv + i8; dst = dq + i8; }
  else              { src = wproj + (i8 - 786432u); dst = dp + (i8 - 786432u); }
  float4 a = *(const float4*)src;
  float4 b = *(const float4*)(src + 4);
  unsigned short pk[8] = {f2bf(a.x), f2bf(a.y), f2bf(a.z), f2bf(a.w),
                          f2bf(b.x), f2bf(b.y), f2bf(b.z), f2bf(b.w)};
  *(uint4*)dst = *(const uint4*)pk;
}

// ---------------------------------------------------------------------------
// prep_xT: x [b][c][n] fp32 -> xT [b][n][c] bf16. 64x64 LDS tile transpose.
// ---------------------------------------------------------------------------
__global__ __launch_bounds__(256) void prep_xT(const float* __restrict__ x,
                                               unsigned short* __restrict__ xT) {
  const int b  = blockIdx.z;
  const int c0 = blockIdx.y * 64;
  const int n0 = blockIdx.x * 64;
  __shared__ float tile[64][65];
  const int t  = threadIdx.x;
  const int cl = t >> 4, n4 = (t & 15) * 4;
#pragma unroll
  for (int r = 0; r < 4; ++r) {
    float4 v = *(const float4*)&x[((size_t)b * CC + c0 + cl + 16 * r) * NN + n0 + n4];
    *(float4*)&tile[cl + 16 * r][n4] = v;
  }
  __syncthreads();
  const int nl = t >> 4, c4 = (t & 15) * 4;
#pragma unroll
  for (int r = 0; r < 4; ++r) {
    ushort4 p;
    p.x = f2bf(tile[c4 + 0][nl + 16 * r]);
    p.y = f2bf(tile[c4 + 1][nl + 16 * r]);
    p.z = f2bf(tile[c4 + 2][nl + 16 * r]);
    p.w = f2bf(tile[c4 + 3][nl + 16 * r]);
    *(ushort4*)&xT[((size_t)b * NN + n0 + nl + 16 * r) * CC + c0 + c4] = p;
  }
}

// ---------------------------------------------------------------------------
// qkv_mfma: [1536x512] @ [512x1024] per batch, bf16 MFMA, 128x128 tile BK=64.
// ---------------------------------------------------------------------------
__global__ __launch_bounds__(256) void qkv_mfma(const unsigned short* __restrict__ wq,
                                                const unsigned short* __restrict__ xT,
                                                unsigned short* __restrict__ qb,
                                                unsigned short* __restrict__ kb_,
                                                unsigned short* __restrict__ vt) {
  const int b  = blockIdx.z;
  const int o0 = blockIdx.y * 128;
  const int n0 = blockIdx.x * 128;
  const int t  = threadIdx.x;
  const int w    = t >> 6;
  const int lane = t & 63;
  const int quad = lane >> 4;
  const int l16  = lane & 15;
  const int m_off = (w >> 1) * 64;
  const int n_off = (w & 1) * 64;

  __shared__ unsigned short sm[17408];
  unsigned short* As = sm;
  unsigned short* Bs = sm + 8192;

  const int which = o0 >> 9;       // 0=Q,1=K,2=V
  const bool vmode = (which == 2);

  const int srow = lane >> 3;
  const int ssw  = ((lane & 7) ^ srow) * 8;
  const unsigned short* gA = wq + (size_t)(o0 + 32 * w + srow) * CC + ssw;
  const unsigned short* gB = xT + ((size_t)b * NN + n0 + 32 * w + srow) * CC + ssw;

  f32x4 acc[4][4] = {};

  for (int c0 = 0; c0 < CC; c0 += 64) {
    __syncthreads();
#pragma unroll
    for (int L = 0; L < 4; ++L) {
      gld_lds16(gA + (size_t)(8 * L) * CC + c0, &As[(32 * w + 8 * L) * 64]);
      gld_lds16(gB + (size_t)(8 * L) * CC + c0, &Bs[(32 * w + 8 * L) * 64]);
    }
    __syncthreads();
    const unsigned short* Af = vmode ? Bs : As;
    const unsigned short* Bf = vmode ? As : Bs;
#pragma unroll
    for (int ks = 0; ks < 2; ++ks) {
      const int ph = ((ks * 4 + quad) ^ (l16 & 7)) * 8;
      bf16x8 af[4], bfr[4];
#pragma unroll
      for (int i = 0; i < 4; ++i) {
        af[i]  = *(const bf16x8*)&Af[(m_off + 16 * i + l16) * 64 + ph];
        bfr[i] = *(const bf16x8*)&Bf[(n_off + 16 * i + l16) * 64 + ph];
      }
#pragma unroll
      for (int i = 0; i < 4; ++i)
#pragma unroll
        for (int j = 0; j < 4; ++j)
          acc[i][j] = __builtin_amdgcn_mfma_f32_16x16x32_bf16(af[i], bfr[j], acc[i][j], 0, 0, 0);
    }
  }

  __syncthreads();
  const float sc = (which == 0) ? QSCALE : 1.0f;
#pragma unroll
  for (int i = 0; i < 4; ++i) {
#pragma unroll
    for (int j = 0; j < 4; ++j) {
      const int Drow = m_off + 16 * i + quad * 4;
      const int Dcol = n_off + 16 * j + l16;
      ushort4 p;
      p.x = f2bf(acc[i][j][0] * sc);
      p.y = f2bf(acc[i][j][1] * sc);
      p.z = f2bf(acc[i][j][2] * sc);
      p.w = f2bf(acc[i][j][3] * sc);
      *(ushort4*)&sm[Dcol * 136 + Drow] = p;
    }
  }
  __syncthreads();
  const int lrow = t >> 1;
  const int half = t & 1;
  const unsigned short* src = &sm[lrow * 136 + 64 * half];
  if (!vmode) {
    const int hh = ((o0 >> 6) & 7) + half;
    unsigned short* dst = (which == 0 ? qb : kb_) +
        ((size_t)(b * NH + hh) * NN + n0 + lrow) * HD;
#pragma unroll
    for (int i = 0; i < 8; ++i) *(uint4*)(dst + 8 * i) = *(const uint4*)(src + 8 * i);
  } else {
    const int hh = ((o0 + lrow) >> 6) & 7;
    const int d  = lrow & 63;
    unsigned short* dst = vt + ((size_t)(b * NH + hh) * HD + d) * NN + n0 + 64 * half;
#pragma unroll
    for (int i = 0; i < 8; ++i) *(uint4*)(dst + 8 * i) = *(const uint4*)(src + 8 * i);
  }
}

// ---------------------------------------------------------------------------
// attn_mfma v8: v4 loop structure (best measured: 60.2us, race-screened)
// + 64 QUERIES PER WAVE. R4 pipe model (validated by v7's counter flip):
// the LDS-read pipe dominates (each wave read the full K/V chunk to serve
// only 32 queries). v8 gives each wave two Q fragments (qfA at w*64+l31,
// qfB at +32): every kf/vf ds_read_b128 now feeds TWO MFMAs, halving
// per-query LDS traffic; per-query MFMA/VALU/exp2 unchanged. Block covers
// 256 queries -> grid (128,4) = 512 blocks = 2 blocks/CU; per-chunk LDS
// reads per CU drop 256KB -> 128KB, chunk staging traffic halves too.
// Double-buffered stage-after-barrier K/V staging + setprio kept from v4.
// Epilogue in two wave-private passes (A then B) to fit 32KB LDS.
// ---------------------------------------------------------------------------
__global__ __launch_bounds__(256, 2) void attn_mfma(const unsigned short* __restrict__ Qg,
                                                    const unsigned short* __restrict__ Kg,
                                                    const unsigned short* __restrict__ Vtg,
                                                    unsigned short* __restrict__ attnB) {
  const int bh = blockIdx.x;     // id % 8 == bh % 8 -> XCD affinity
  const int b  = bh >> 3;
  const int h  = bh & 7;
  const int n0 = blockIdx.y * 256;
  const int t  = threadIdx.x;
  const int w    = t >> 6;
  const int lane = t & 63;
  const int l31  = lane & 31;
  const int hi   = lane >> 5;

  // kb0 = sm[0,4096), kb1 = sm[4096,8192), vb0 = sm[8192,12288), vb1 = rest
  __shared__ unsigned short sm[16384];

  // two query groups per wave: A = n0 + w*64 + l31, B = A + 32
  const unsigned short* qrow = Qg + ((size_t)bh * NN + n0 + w * 64 + l31) * HD + hi * 8;
  bf16x8 qfA[4], qfB[4];
#pragma unroll
  for (int c = 0; c < 4; ++c) {
    qfA[c] = *(const bf16x8*)(qrow + 16 * c);
    qfB[c] = *(const bf16x8*)(qrow + 32 * HD + 16 * c);
  }

  // K A-row permutation: rho(l) swaps bits 2 and 3
  const int krow = (l31 & ~12) | ((l31 & 4) << 1) | ((l31 & 8) >> 1);
  const int ksw  = krow & 7;
  const int vsw  = l31 & 7;

  const f32x16 fz = {};
  f32x16 oaccA[2] = {}, oaccB[2] = {};   // O^T: D[m=d][n=query]
  float lxA = 0.f, lyA = 0.f, lxB = 0.f, lyB = 0.f;

  // staging: wave w covers rows [16w,16w+16) of both K (keys) and V^T (d).
  const int srow = lane >> 3;                     // 0..7
  const int sgrp = (lane & 7) ^ (srow & 7);       // swizzled source col group
  const unsigned short* kstage = Kg + (size_t)bh * NN * HD +
                                 (size_t)(16 * w + srow) * HD + sgrp * 8;
  const unsigned short* vstage = Vtg + (size_t)bh * HD * NN +
                                 (size_t)(16 * w + srow) * NN + sgrp * 8;
  const int kso0 = (16 * w) * 64;
  const int kso1 = (16 * w + 8) * 64;

  auto stage = [&](int j0, int p) {
    unsigned short* Kp = sm + p * 4096;
    unsigned short* Vp = sm + 8192 + p * 4096;
    gld_lds16(kstage + (size_t)j0 * HD, Kp + kso0);
    gld_lds16(kstage + (size_t)(j0 + 8) * HD, Kp + kso1);
    gld_lds16(vstage + j0, Vp + kso0);
    gld_lds16(vstage + (size_t)8 * NN + j0, Vp + kso1);
  };

  // prologue: chunk 0 into buffer 0
  stage(0, 0);
  int cur = 0;

#pragma unroll 1
  for (int j0 = 0; j0 < NN; j0 += 64) {
    // implicit s_waitcnt vmcnt(0) here drains chunk-j0 loads (in flight for
    // a full compute phase), then publishes them to all waves.
    __syncthreads();
    if (j0 + 64 < NN) stage(j0 + 64, cur ^ 1);   // overwrite chunk j0-64's buf

    const unsigned short* Ks = sm + cur * 4096;         // [key][d] swz rows
    const unsigned short* Vt = sm + 8192 + cur * 4096;  // [d][key] swz rows

#pragma unroll
    for (int kb = 0; kb < 2; ++kb) {
      // S^T: A[m]=K row rho(m) (32 keys), B=Q; contract over d.
      // kf read ONCE from LDS, feeds both query groups.
      const unsigned short* krp = &Ks[(32 * kb + krow) * 64];
      __builtin_amdgcn_s_setprio(1);
      bf16x8 kf0 = *(const bf16x8*)(krp + (((0 + hi) ^ ksw) * 8));
      f32x16 stA = __builtin_amdgcn_mfma_f32_32x32x16_bf16(kf0, qfA[0], fz, 0, 0, 0);
      f32x16 stB = __builtin_amdgcn_mfma_f32_32x32x16_bf16(kf0, qfB[0], fz, 0, 0, 0);
#pragma unroll
      for (int c = 1; c < 4; ++c) {
        bf16x8 kf = *(const bf16x8*)(krp + (((2 * c + hi) ^ ksw) * 8));
        stA = __builtin_amdgcn_mfma_f32_32x32x16_bf16(kf, qfA[c], stA, 0, 0, 0);
        stB = __builtin_amdgcn_mfma_f32_32x32x16_bf16(kf, qfB[c], stB, 0, 0, 0);
      }
      __builtin_amdgcn_s_setprio(0);
      // exp2 (Q carries log2e/8) + l accum + pack; P pairs ARE the PV
      // B-fragment (key permutation absorbed rho)
      unsigned PA[8], PB[8];
#pragma unroll
      for (int i = 0; i < 8; ++i) {
        float ea = EXP2F(stA[2 * i]);
        float eb = EXP2F(stA[2 * i + 1]);
        lxA += ea; lyA += eb;
        PA[i] = pk2bf(ea, eb);
      }
#pragma unroll
      for (int i = 0; i < 8; ++i) {
        float ea = EXP2F(stB[2 * i]);
        float eb = EXP2F(stB[2 * i + 1]);
        lxB += ea; lyB += eb;
        PB[i] = pk2bf(ea, eb);
      }

      __builtin_amdgcn_s_setprio(1);
#pragma unroll
      for (int g = 0; g < 2; ++g) {
        union { unsigned u[4]; bf16x8 v; } cvA, cvB;
        cvA.u[0] = PA[4 * g + 0]; cvA.u[1] = PA[4 * g + 1];
        cvA.u[2] = PA[4 * g + 2]; cvA.u[3] = PA[4 * g + 3];
        cvB.u[0] = PB[4 * g + 0]; cvB.u[1] = PB[4 * g + 1];
        cvB.u[2] = PB[4 * g + 2]; cvB.u[3] = PB[4 * g + 3];
#pragma unroll
        for (int mt = 0; mt < 2; ++mt) {
          const int vrow = 32 * mt + l31;
          // vf read ONCE from LDS, feeds both query groups.
          bf16x8 vf = *(const bf16x8*)&Vt[vrow * 64 + (((4 * kb + 2 * g + hi) ^ vsw) * 8)];
          oaccA[mt] = __builtin_amdgcn_mfma_f32_32x32x16_bf16(vf, cvA.v, oaccA[mt], 0, 0, 0);
          oaccB[mt] = __builtin_amdgcn_mfma_f32_32x32x16_bf16(vf, cvB.v, oaccB[mt], 0, 0, 0);
        }
      }
      __builtin_amdgcn_s_setprio(0);
    }
    cur ^= 1;
  }

  float lsA = lxA + lyA;
  lsA += __shfl_xor(lsA, 32);
  const float invA = 1.0f / lsA;
  float lsB = lxB + lyB;
  lsB += __shfl_xor(lsB, 32);
  const float invB = 1.0f / lsB;

  // epilogue: two wave-private passes through LDS [query][d] (pitch 72),
  // then 64B global writes. Barrier first: staging buffers overlap Es.
  __syncthreads();
  unsigned short* Es = sm + w * 2304;   // 32 * 72 shorts per wave
  const int q    = lane >> 1;
  const int half = lane & 1;
  const unsigned short* esrc = &Es[q * 72 + 32 * half];

  // ---- pass A ----
#pragma unroll
  for (int mt = 0; mt < 2; ++mt) {
#pragma unroll
    for (int rr = 0; rr < 4; ++rr) {
      const int d = 32 * mt + 8 * rr + 4 * hi;
      ushort4 p;
      p.x = f2bf(oaccA[mt][4 * rr + 0] * invA);
      p.y = f2bf(oaccA[mt][4 * rr + 1] * invA);
      p.z = f2bf(oaccA[mt][4 * rr + 2] * invA);
      p.w = f2bf(oaccA[mt][4 * rr + 3] * invA);
      *(ushort4*)&Es[l31 * 72 + d] = p;
    }
  }
  {
    unsigned short* gdst = attnB + ((size_t)b * NN + n0 + w * 64 + q) * CC + h * HD + 32 * half;
#pragma unroll
    for (int i = 0; i < 4; ++i) *(uint4*)(gdst + 8 * i) = *(const uint4*)(esrc + 8 * i);
  }

  // ---- pass B (same wave-private region; in-wave deps order LDS ops) ----
#pragma unroll
  for (int mt = 0; mt < 2; ++mt) {
#pragma unroll
    for (int rr = 0; rr < 4; ++rr) {
      const int d = 32 * mt + 8 * rr + 4 * hi;
      ushort4 p;
      p.x = f2bf(oaccB[mt][4 * rr + 0] * invB);
      p.y = f2bf(oaccB[mt][4 * rr + 1] * invB);
      p.z = f2bf(oaccB[mt][4 * rr + 2] * invB);
      p.w = f2bf(oaccB[mt][4 * rr + 3] * invB);
      *(ushort4*)&Es[l31 * 72 + d] = p;
    }
  }
  {
    unsigned short* gdst = attnB + ((size_t)b * NN + n0 + w * 64 + 32 + q) * CC + h * HD + 32 * half;
#pragma unroll
    for (int i = 0; i < 4; ++i) *(uint4*)(gdst + 8 * i) = *(const uint4*)(esrc + 8 * i);
  }
}

// ---------------------------------------------------------------------------
// proj_mfma: out = w_proj @ attn + bias, bf16 MFMA, fp32 out [b][c][n].
// ---------------------------------------------------------------------------
__global__ __launch_bounds__(256) void proj_mfma(const unsigned short* __restrict__ wp,
                                                 const unsigned short* __restrict__ aB,
                                                 const float* __restrict__ bias,
                                                 float* __restrict__ out) {
  const int b  = blockIdx.z;
  const int o0 = blockIdx.y * 128;
  const int n0 = blockIdx.x * 128;
  const int t  = threadIdx.x;
  const int w    = t >> 6;
  const int lane = t & 63;
  const int quad = lane >> 4;
  const int l16  = lane & 15;
  const int m_off = (w >> 1) * 64;
  const int n_off = (w & 1) * 64;

  __shared__ unsigned short sm[16384];
  unsigned short* As = sm;
  unsigned short* Bs = sm + 8192;

  const int srow = lane >> 3;
  const int ssw  = ((lane & 7) ^ srow) * 8;
  const unsigned short* gA = wp + (size_t)(o0 + 32 * w + srow) * CC + ssw;
  const unsigned short* gB = aB + ((size_t)b * NN + n0 + 32 * w + srow) * CC + ssw;

  f32x4 acc[4][4] = {};

  for (int c0 = 0; c0 < CC; c0 += 64) {
    __syncthreads();
#pragma unroll
    for (int L = 0; L < 4; ++L) {
      gld_lds16(gA + (size_t)(8 * L) * CC + c0, &As[(32 * w + 8 * L) * 64]);
      gld_lds16(gB + (size_t)(8 * L) * CC + c0, &Bs[(32 * w + 8 * L) * 64]);
    }
    __syncthreads();
#pragma unroll
    for (int ks = 0; ks < 2; ++ks) {
      const int ph = ((ks * 4 + quad) ^ (l16 & 7)) * 8;
      bf16x8 af[4], bfr[4];
#pragma unroll
      for (int i = 0; i < 4; ++i) {
        af[i]  = *(const bf16x8*)&As[(m_off + 16 * i + l16) * 64 + ph];
        bfr[i] = *(const bf16x8*)&Bs[(n_off + 16 * i + l16) * 64 + ph];
      }
#pragma unroll
      for (int i = 0; i < 4; ++i)
#pragma unroll
        for (int j = 0; j < 4; ++j)
          acc[i][j] = __builtin_amdgcn_mfma_f32_16x16x32_bf16(af[i], bfr[j], acc[i][j], 0, 0, 0);
    }
  }

#pragma unroll
  for (int i = 0; i < 4; ++i) {
#pragma unroll
    for (int r = 0; r < 4; ++r) {
      const int o = o0 + m_off + 16 * i + quad * 4 + r;
      const float bv = bias[o];
      float* orow = out + ((size_t)b * CC + o) * NN + n0 + n_off;
#pragma unroll
      for (int j = 0; j < 4; ++j)
        orow[16 * j + l16] = acc[i][j][r] + bv;
    }
  }
}

// ---------------------------------------------------------------------------
extern "C" void kernel_launch(void* const* d_in, const int* in_sizes, int n_in,
                              void* d_out, int out_size, void* d_ws, size_t ws_size,
                              hipStream_t stream) {
  const float* x      = (const float*)d_in[0];
  const float* w_qkv  = (const float*)d_in[1];
  const float* w_proj = (const float*)d_in[2];
  const float* b_proj = (const float*)d_in[3];
  char* wsb  = (char*)d_ws;
  float* out = (float*)d_out;

  unsigned short* xT  = (unsigned short*)(wsb + XT_OFF);
  unsigned short* wq  = (unsigned short*)(wsb + WQ_OFF);
  unsigned short* wp  = (unsigned short*)(wsb + WP_OFF);
  unsigned short* qb  = (unsigned short*)(wsb + QB_OFF);
  unsigned short* kb_ = (unsigned short*)(wsb + KB_OFF);
  unsigned short* vt  = (unsigned short*)(wsb + VT_OFF);
  unsigned short* aB  = (unsigned short*)(wsb + AB_OFF);

  prep_w<<<512, 256, 0, stream>>>(w_qkv, w_proj, wq, wp);
  prep_xT<<<dim3(16, 8, BB), 256, 0, stream>>>(x, xT);
  qkv_mfma<<<dim3(8, 12, BB), 256, 0, stream>>>(wq, xT, qb, kb_, vt);
  attn_mfma<<<dim3(BB * NH, NN / 256), 256, 0, stream>>>(qb, kb_, vt, aB);
  proj_mfma<<<dim3(8, 4, BB), 256, 0, stream>>>(wp, aB, b_proj, out);
}

// Round 6
// 189.452 us; speedup vs baseline: 1.4224x; 1.0109x over previous
//
#include <hip/hip_runtime.h>
#include <hip/hip_bf16.h>
#include <math.h>

#define BB 16
#define CC 512
#define NH 8
#define HD 64
#define NN 1024   // H*W
#define THREEC 1536

// Q pre-scale: (1/sqrt(64)) * log2(e)  -> softmax via raw v_exp_f32 (2^x)
#define QSCALE 0.18033688f

typedef __attribute__((ext_vector_type(8))) short bf16x8;
typedef __attribute__((ext_vector_type(4))) float f32x4;
typedef __attribute__((ext_vector_type(16))) float f32x16;

#if __has_builtin(__builtin_amdgcn_exp2f)
#define EXP2F __builtin_amdgcn_exp2f
#else
#define EXP2F exp2f
#endif

// workspace byte offsets
#define XT_OFF 0u           // bf16 x^T [b][n][c]          (16.78 MB)
#define WQ_OFF 16777216u    // bf16 w_qkv [1536][512]      (1.57 MB)
#define WP_OFF 18350080u    // bf16 w_proj [512][512]      (0.52 MB)
#define QB_OFF 18874368u    // bf16 Q (scaled QSCALE) [bh][n][d]
#define KB_OFF 35651584u    // bf16 K [bh][n][d]
#define VT_OFF 52428800u    // bf16 V^T [bh][d][n]
#define AB_OFF 69206016u    // bf16 attn-out [b][n][c]
// end 85983232 (82 MiB)

static __device__ inline unsigned short f2bf(float f) {
  union { float f; unsigned u; } v; v.f = f;
  unsigned r = v.u + 0x7fffu + ((v.u >> 16) & 1u);
  return (unsigned short)(r >> 16);
}

// pack two f32 -> two bf16 in a u32 (lo = a, hi = b)
static __device__ inline unsigned pk2bf(float a, float b) {
#if defined(__AMDGCN__) && __has_builtin(__builtin_amdgcn_cvt_pk_bf16_f32)
  typedef __attribute__((ext_vector_type(2))) __bf16 bfp2;
  union { bfp2 v; unsigned u; } z;
  z.v = __builtin_amdgcn_cvt_pk_bf16_f32(a, b);
  return z.u;
#else
  return (unsigned)f2bf(a) | ((unsigned)f2bf(b) << 16);
#endif
}

static __device__ inline void gld_lds16(const unsigned short* g, unsigned short* l) {
  __builtin_amdgcn_global_load_lds(
      (const __attribute__((address_space(1))) unsigned int*)g,
      (__attribute__((address_space(3))) unsigned int*)l, 16, 0, 0);
}

// ---------------------------------------------------------------------------
// prep_w: convert w_qkv (786432) + w_proj (262144) fp32 -> bf16
// ---------------------------------------------------------------------------
__global__ __launch_bounds__(256) void prep_w(const float* __restrict__ wqkv,
                                              const float* __restrict__ wproj,
                                              unsigned short* __restrict__ dq,
                                              unsigned short* __restrict__ dp) {
  const size_t i8 = ((size_t)blockIdx.x * 256 + threadIdx.x) * 8;
  const float* src;
  unsigned short* dst;
  if (i8 < 786432u) { src = wqkv + i8; dst = dq + i8; }
  else              { src = wproj + (i8 - 786432u); dst = dp + (i8 - 786432u); }
  float4 a = *(const float4*)src;
  float4 b = *(const float4*)(src + 4);
  unsigned short pk[8] = {f2bf(a.x), f2bf(a.y), f2bf(a.z), f2bf(a.w),
                          f2bf(b.x), f2bf(b.y), f2bf(b.z), f2bf(b.w)};
  *(uint4*)dst = *(const uint4*)pk;
}

// ---------------------------------------------------------------------------
// prep_xT: x [b][c][n] fp32 -> xT [b][n][c] bf16. 64x64 LDS tile transpose.
// ---------------------------------------------------------------------------
__global__ __launch_bounds__(256) void prep_xT(const float* __restrict__ x,
                                               unsigned short* __restrict__ xT) {
  const int b  = blockIdx.z;
  const int c0 = blockIdx.y * 64;
  const int n0 = blockIdx.x * 64;
  __shared__ float tile[64][65];
  const int t  = threadIdx.x;
  const int cl = t >> 4, n4 = (t & 15) * 4;
#pragma unroll
  for (int r = 0; r < 4; ++r) {
    float4 v = *(const float4*)&x[((size_t)b * CC + c0 + cl + 16 * r) * NN + n0 + n4];
    *(float4*)&tile[cl + 16 * r][n4] = v;
  }
  __syncthreads();
  const int nl = t >> 4, c4 = (t & 15) * 4;
#pragma unroll
  for (int r = 0; r < 4; ++r) {
    ushort4 p;
    p.x = f2bf(tile[c4 + 0][nl + 16 * r]);
    p.y = f2bf(tile[c4 + 1][nl + 16 * r]);
    p.z = f2bf(tile[c4 + 2][nl + 16 * r]);
    p.w = f2bf(tile[c4 + 3][nl + 16 * r]);
    *(ushort4*)&xT[((size_t)b * NN + n0 + nl + 16 * r) * CC + c0 + c4] = p;
  }
}

// ---------------------------------------------------------------------------
// qkv_mfma: [1536x512] @ [512x1024] per batch, bf16 MFMA, 128x128 tile BK=64.
// ---------------------------------------------------------------------------
__global__ __launch_bounds__(256) void qkv_mfma(const unsigned short* __restrict__ wq,
                                                const unsigned short* __restrict__ xT,
                                                unsigned short* __restrict__ qb,
                                                unsigned short* __restrict__ kb_,
                                                unsigned short* __restrict__ vt) {
  const int b  = blockIdx.z;
  const int o0 = blockIdx.y * 128;
  const int n0 = blockIdx.x * 128;
  const int t  = threadIdx.x;
  const int w    = t >> 6;
  const int lane = t & 63;
  const int quad = lane >> 4;
  const int l16  = lane & 15;
  const int m_off = (w >> 1) * 64;
  const int n_off = (w & 1) * 64;

  __shared__ unsigned short sm[17408];
  unsigned short* As = sm;
  unsigned short* Bs = sm + 8192;

  const int which = o0 >> 9;       // 0=Q,1=K,2=V
  const bool vmode = (which == 2);

  const int srow = lane >> 3;
  const int ssw  = ((lane & 7) ^ srow) * 8;
  const unsigned short* gA = wq + (size_t)(o0 + 32 * w + srow) * CC + ssw;
  const unsigned short* gB = xT + ((size_t)b * NN + n0 + 32 * w + srow) * CC + ssw;

  f32x4 acc[4][4] = {};

  for (int c0 = 0; c0 < CC; c0 += 64) {
    __syncthreads();
#pragma unroll
    for (int L = 0; L < 4; ++L) {
      gld_lds16(gA + (size_t)(8 * L) * CC + c0, &As[(32 * w + 8 * L) * 64]);
      gld_lds16(gB + (size_t)(8 * L) * CC + c0, &Bs[(32 * w + 8 * L) * 64]);
    }
    __syncthreads();
    const unsigned short* Af = vmode ? Bs : As;
    const unsigned short* Bf = vmode ? As : Bs;
#pragma unroll
    for (int ks = 0; ks < 2; ++ks) {
      const int ph = ((ks * 4 + quad) ^ (l16 & 7)) * 8;
      bf16x8 af[4], bfr[4];
#pragma unroll
      for (int i = 0; i < 4; ++i) {
        af[i]  = *(const bf16x8*)&Af[(m_off + 16 * i + l16) * 64 + ph];
        bfr[i] = *(const bf16x8*)&Bf[(n_off + 16 * i + l16) * 64 + ph];
      }
#pragma unroll
      for (int i = 0; i < 4; ++i)
#pragma unroll
        for (int j = 0; j < 4; ++j)
          acc[i][j] = __builtin_amdgcn_mfma_f32_16x16x32_bf16(af[i], bfr[j], acc[i][j], 0, 0, 0);
    }
  }

  __syncthreads();
  const float sc = (which == 0) ? QSCALE : 1.0f;
#pragma unroll
  for (int i = 0; i < 4; ++i) {
#pragma unroll
    for (int j = 0; j < 4; ++j) {
      const int Drow = m_off + 16 * i + quad * 4;
      const int Dcol = n_off + 16 * j + l16;
      ushort4 p;
      p.x = f2bf(acc[i][j][0] * sc);
      p.y = f2bf(acc[i][j][1] * sc);
      p.z = f2bf(acc[i][j][2] * sc);
      p.w = f2bf(acc[i][j][3] * sc);
      *(ushort4*)&sm[Dcol * 136 + Drow] = p;
    }
  }
  __syncthreads();
  const int lrow = t >> 1;
  const int half = t & 1;
  const unsigned short* src = &sm[lrow * 136 + 64 * half];
  if (!vmode) {
    const int hh = ((o0 >> 6) & 7) + half;
    unsigned short* dst = (which == 0 ? qb : kb_) +
        ((size_t)(b * NH + hh) * NN + n0 + lrow) * HD;
#pragma unroll
    for (int i = 0; i < 8; ++i) *(uint4*)(dst + 8 * i) = *(const uint4*)(src + 8 * i);
  } else {
    const int hh = ((o0 + lrow) >> 6) & 7;
    const int d  = lrow & 63;
    unsigned short* dst = vt + ((size_t)(b * NH + hh) * HD + d) * NN + n0 + 64 * half;
#pragma unroll
    for (int i = 0; i < 8; ++i) *(uint4*)(dst + 8 * i) = *(const uint4*)(src + 8 * i);
  }
}

// ---------------------------------------------------------------------------
// attn_mfma v9: v8 (64 q/wave, dbuf stage-after-barrier) +
// (a) CONFLICT-FREE LDS swizzle: slot = (group) ^ ((row>>2)&7) instead of
//     ^(row&7). Position mod 512B = (row mod 4, slot) and (row mod 4,
//     row>>2) <-> row is bijective, so the 32 lanes of each QK/PV
//     ds_read_b128 (rows = permutation of 0..31) hit 32 DISTINCT 16B slots
//     -> zero bank conflicts (was structural 4-way = 2.29M conflict-cycles).
//     Writer side pre-swizzles the global source col per 8-row call:
//     sgrp = (lane&7) ^ ((4w + 2*call + (srow>>2))&7)  [rule #21: same
//     involution on source and read].
// (b) CHUNK=128 as two independent 64-key halves (identical per-half
//     formulas): LDS 2dbuf x (16K K + 16K V) = 64KB, still 2 blocks/CU
//     (grid-limited), barriers 16 -> 8, prefetch has a full 128-key
//     compute phase in flight.
// ---------------------------------------------------------------------------
__global__ __launch_bounds__(256, 2) void attn_mfma(const unsigned short* __restrict__ Qg,
                                                    const unsigned short* __restrict__ Kg,
                                                    const unsigned short* __restrict__ Vtg,
                                                    unsigned short* __restrict__ attnB) {
  const int bh = blockIdx.x;     // id % 8 == bh % 8 -> XCD affinity
  const int b  = bh >> 3;
  const int h  = bh & 7;
  const int n0 = blockIdx.y * 256;
  const int t  = threadIdx.x;
  const int w    = t >> 6;
  const int lane = t & 63;
  const int l31  = lane & 31;
  const int hi   = lane >> 5;

  // K bufs: p*8192 + half*4096  (sm[0,16384))
  // V bufs: 16384 + p*8192 + half*4096  (sm[16384,32768))
  __shared__ unsigned short sm[32768];   // 64 KiB

  // two query groups per wave: A = n0 + w*64 + l31, B = A + 32
  const unsigned short* qrow = Qg + ((size_t)bh * NN + n0 + w * 64 + l31) * HD + hi * 8;
  bf16x8 qfA[4], qfB[4];
#pragma unroll
  for (int c = 0; c < 4; ++c) {
    qfA[c] = *(const bf16x8*)(qrow + 16 * c);
    qfB[c] = *(const bf16x8*)(qrow + 32 * HD + 16 * c);
  }

  // K A-row permutation: rho(l) swaps bits 2 and 3
  const int krow = (l31 & ~12) | ((l31 & 4) << 1) | ((l31 & 8) >> 1);
  const int ksw  = (krow >> 2) & 7;   // conflict-free swizzle (row>>2)
  const int vsw  = (l31 >> 2) & 7;

  const f32x16 fz = {};
  f32x16 oaccA[2] = {}, oaccB[2] = {};   // O^T: D[m=d][n=query]
  float lxA = 0.f, lyA = 0.f, lxB = 0.f, lyB = 0.f;

  // staging: wave w covers rows [16w,16w+16) of both K (keys) and V^T (d),
  // per 64-row half. Source col pre-swizzled with the (row>>2) involution:
  // call A rows 16w+srow   -> C = (4w + (srow>>2)) & 7
  // call B rows 16w+8+srow -> C = (4w + 2 + (srow>>2)) & 7
  const int srow = lane >> 3;                     // 0..7
  const int sgA  = (lane & 7) ^ ((4 * w + (srow >> 2)) & 7);
  const int sgB  = (lane & 7) ^ ((4 * w + 2 + (srow >> 2)) & 7);
  const unsigned short* kstA = Kg + (size_t)bh * NN * HD +
                               (size_t)(16 * w + srow) * HD + sgA * 8;
  const unsigned short* kstB = Kg + (size_t)bh * NN * HD +
                               (size_t)(16 * w + 8 + srow) * HD + sgB * 8;
  const unsigned short* vstA = Vtg + (size_t)bh * HD * NN +
                               (size_t)(16 * w + srow) * NN + sgA * 8;
  const unsigned short* vstB = Vtg + (size_t)bh * HD * NN +
                               (size_t)(16 * w + 8 + srow) * NN + sgB * 8;
  const int kso0 = (16 * w) * 64;
  const int kso1 = (16 * w + 8) * 64;

  // stage one 128-key chunk (two 64-key halves) into buffer p
  auto stage = [&](int j0, int p) {
#pragma unroll
    for (int hf = 0; hf < 2; ++hf) {
      unsigned short* Kp = sm + p * 8192 + hf * 4096;
      unsigned short* Vp = sm + 16384 + p * 8192 + hf * 4096;
      const int jo = j0 + 64 * hf;
      gld_lds16(kstA + (size_t)jo * HD, Kp + kso0);
      gld_lds16(kstB + (size_t)jo * HD, Kp + kso1);
      gld_lds16(vstA + jo, Vp + kso0);
      gld_lds16(vstB + jo, Vp + kso1);
    }
  };

  // prologue: chunk 0 into buffer 0
  stage(0, 0);
  int cur = 0;

#pragma unroll 1
  for (int j0 = 0; j0 < NN; j0 += 128) {
    // implicit s_waitcnt vmcnt(0) here drains chunk-j0 loads (in flight for
    // a full 128-key compute phase), then publishes them to all waves.
    __syncthreads();
    if (j0 + 128 < NN) stage(j0 + 128, cur ^ 1);

#pragma unroll
    for (int hf = 0; hf < 2; ++hf) {
      const unsigned short* Ks = sm + cur * 8192 + hf * 4096;          // [key][d]
      const unsigned short* Vt = sm + 16384 + cur * 8192 + hf * 4096;  // [d][key]

#pragma unroll
      for (int kb = 0; kb < 2; ++kb) {
        // S^T: A[m]=K row rho(m) (32 keys), B=Q; contract over d.
        // kf read ONCE from LDS, feeds both query groups.
        const unsigned short* krp = &Ks[(32 * kb + krow) * 64];
        __builtin_amdgcn_s_setprio(1);
        bf16x8 kf0 = *(const bf16x8*)(krp + (((0 + hi) ^ ksw) * 8));
        f32x16 stA = __builtin_amdgcn_mfma_f32_32x32x16_bf16(kf0, qfA[0], fz, 0, 0, 0);
        f32x16 stB = __builtin_amdgcn_mfma_f32_32x32x16_bf16(kf0, qfB[0], fz, 0, 0, 0);
#pragma unroll
        for (int c = 1; c < 4; ++c) {
          bf16x8 kf = *(const bf16x8*)(krp + (((2 * c + hi) ^ ksw) * 8));
          stA = __builtin_amdgcn_mfma_f32_32x32x16_bf16(kf, qfA[c], stA, 0, 0, 0);
          stB = __builtin_amdgcn_mfma_f32_32x32x16_bf16(kf, qfB[c], stB, 0, 0, 0);
        }
        __builtin_amdgcn_s_setprio(0);
        // exp2 (Q carries log2e/8) + l accum + pack; P pairs ARE the PV
        // B-fragment (key permutation absorbed rho)
        unsigned PA[8], PB[8];
#pragma unroll
        for (int i = 0; i < 8; ++i) {
          float ea = EXP2F(stA[2 * i]);
          float eb = EXP2F(stA[2 * i + 1]);
          lxA += ea; lyA += eb;
          PA[i] = pk2bf(ea, eb);
        }
#pragma unroll
        for (int i = 0; i < 8; ++i) {
          float ea = EXP2F(stB[2 * i]);
          float eb = EXP2F(stB[2 * i + 1]);
          lxB += ea; lyB += eb;
          PB[i] = pk2bf(ea, eb);
        }

        __builtin_amdgcn_s_setprio(1);
#pragma unroll
        for (int g = 0; g < 2; ++g) {
          union { unsigned u[4]; bf16x8 v; } cvA, cvB;
          cvA.u[0] = PA[4 * g + 0]; cvA.u[1] = PA[4 * g + 1];
          cvA.u[2] = PA[4 * g + 2]; cvA.u[3] = PA[4 * g + 3];
          cvB.u[0] = PB[4 * g + 0]; cvB.u[1] = PB[4 * g + 1];
          cvB.u[2] = PB[4 * g + 2]; cvB.u[3] = PB[4 * g + 3];
#pragma unroll
          for (int mt = 0; mt < 2; ++mt) {
            const int vrow = 32 * mt + l31;
            // vf read ONCE from LDS, feeds both query groups.
            bf16x8 vf = *(const bf16x8*)&Vt[vrow * 64 + (((4 * kb + 2 * g + hi) ^ vsw) * 8)];
            oaccA[mt] = __builtin_amdgcn_mfma_f32_32x32x16_bf16(vf, cvA.v, oaccA[mt], 0, 0, 0);
            oaccB[mt] = __builtin_amdgcn_mfma_f32_32x32x16_bf16(vf, cvB.v, oaccB[mt], 0, 0, 0);
          }
        }
        __builtin_amdgcn_s_setprio(0);
      }
    }
    cur ^= 1;
  }

  float lsA = lxA + lyA;
  lsA += __shfl_xor(lsA, 32);
  const float invA = 1.0f / lsA;
  float lsB = lxB + lyB;
  lsB += __shfl_xor(lsB, 32);
  const float invB = 1.0f / lsB;

  // epilogue: two wave-private passes through LDS [query][d] (pitch 72),
  // then 64B global writes. Barrier first: staging buffers overlap Es.
  __syncthreads();
  unsigned short* Es = sm + w * 2304;   // 32 * 72 shorts per wave
  const int q    = lane >> 1;
  const int half = lane & 1;
  const unsigned short* esrc = &Es[q * 72 + 32 * half];

  // ---- pass A ----
#pragma unroll
  for (int mt = 0; mt < 2; ++mt) {
#pragma unroll
    for (int rr = 0; rr < 4; ++rr) {
      const int d = 32 * mt + 8 * rr + 4 * hi;
      ushort4 p;
      p.x = f2bf(oaccA[mt][4 * rr + 0] * invA);
      p.y = f2bf(oaccA[mt][4 * rr + 1] * invA);
      p.z = f2bf(oaccA[mt][4 * rr + 2] * invA);
      p.w = f2bf(oaccA[mt][4 * rr + 3] * invA);
      *(ushort4*)&Es[l31 * 72 + d] = p;
    }
  }
  {
    unsigned short* gdst = attnB + ((size_t)b * NN + n0 + w * 64 + q) * CC + h * HD + 32 * half;
#pragma unroll
    for (int i = 0; i < 4; ++i) *(uint4*)(gdst + 8 * i) = *(const uint4*)(esrc + 8 * i);
  }

  // ---- pass B (same wave-private region; in-wave deps order LDS ops) ----
#pragma unroll
  for (int mt = 0; mt < 2; ++mt) {
#pragma unroll
    for (int rr = 0; rr < 4; ++rr) {
      const int d = 32 * mt + 8 * rr + 4 * hi;
      ushort4 p;
      p.x = f2bf(oaccB[mt][4 * rr + 0] * invB);
      p.y = f2bf(oaccB[mt][4 * rr + 1] * invB);
      p.z = f2bf(oaccB[mt][4 * rr + 2] * invB);
      p.w = f2bf(oaccB[mt][4 * rr + 3] * invB);
      *(ushort4*)&Es[l31 * 72 + d] = p;
    }
  }
  {
    unsigned short* gdst = attnB + ((size_t)b * NN + n0 + w * 64 + 32 + q) * CC + h * HD + 32 * half;
#pragma unroll
    for (int i = 0; i < 4; ++i) *(uint4*)(gdst + 8 * i) = *(const uint4*)(esrc + 8 * i);
  }
}

// ---------------------------------------------------------------------------
// proj_mfma: out = w_proj @ attn + bias, bf16 MFMA, fp32 out [b][c][n].
// ---------------------------------------------------------------------------
__global__ __launch_bounds__(256) void proj_mfma(const unsigned short* __restrict__ wp,
                                                 const unsigned short* __restrict__ aB,
                                                 const float* __restrict__ bias,
                                                 float* __restrict__ out) {
  const int b  = blockIdx.z;
  const int o0 = blockIdx.y * 128;
  const int n0 = blockIdx.x * 128;
  const int t  = threadIdx.x;
  const int w    = t >> 6;
  const int lane = t & 63;
  const int quad = lane >> 4;
  const int l16  = lane & 15;
  const int m_off = (w >> 1) * 64;
  const int n_off = (w & 1) * 64;

  __shared__ unsigned short sm[16384];
  unsigned short* As = sm;
  unsigned short* Bs = sm + 8192;

  const int srow = lane >> 3;
  const int ssw  = ((lane & 7) ^ srow) * 8;
  const unsigned short* gA = wp + (size_t)(o0 + 32 * w + srow) * CC + ssw;
  const unsigned short* gB = aB + ((size_t)b * NN + n0 + 32 * w + srow) * CC + ssw;

  f32x4 acc[4][4] = {};

  for (int c0 = 0; c0 < CC; c0 += 64) {
    __syncthreads();
#pragma unroll
    for (int L = 0; L < 4; ++L) {
      gld_lds16(gA + (size_t)(8 * L) * CC + c0, &As[(32 * w + 8 * L) * 64]);
      gld_lds16(gB + (size_t)(8 * L) * CC + c0, &Bs[(32 * w + 8 * L) * 64]);
    }
    __syncthreads();
#pragma unroll
    for (int ks = 0; ks < 2; ++ks) {
      const int ph = ((ks * 4 + quad) ^ (l16 & 7)) * 8;
      bf16x8 af[4], bfr[4];
#pragma unroll
      for (int i = 0; i < 4; ++i) {
        af[i]  = *(const bf16x8*)&As[(m_off + 16 * i + l16) * 64 + ph];
        bfr[i] = *(const bf16x8*)&Bs[(n_off + 16 * i + l16) * 64 + ph];
      }
#pragma unroll
      for (int i = 0; i < 4; ++i)
#pragma unroll
        for (int j = 0; j < 4; ++j)
          acc[i][j] = __builtin_amdgcn_mfma_f32_16x16x32_bf16(af[i], bfr[j], acc[i][j], 0, 0, 0);
    }
  }

#pragma unroll
  for (int i = 0; i < 4; ++i) {
#pragma unroll
    for (int r = 0; r < 4; ++r) {
      const int o = o0 + m_off + 16 * i + quad * 4 + r;
      const float bv = bias[o];
      float* orow = out + ((size_t)b * CC + o) * NN + n0 + n_off;
#pragma unroll
      for (int j = 0; j < 4; ++j)
        orow[16 * j + l16] = acc[i][j][r] + bv;
    }
  }
}

// ---------------------------------------------------------------------------
extern "C" void kernel_launch(void* const* d_in, const int* in_sizes, int n_in,
                              void* d_out, int out_size, void* d_ws, size_t ws_size,
                              hipStream_t stream) {
  const float* x      = (const float*)d_in[0];
  const float* w_qkv  = (const float*)d_in[1];
  const float* w_proj = (const float*)d_in[2];
  const float* b_proj = (const float*)d_in[3];
  char* wsb  = (char*)d_ws;
  float* out = (float*)d_out;

  unsigned short* xT  = (unsigned short*)(wsb + XT_OFF);
  unsigned short* wq  = (unsigned short*)(wsb + WQ_OFF);
  unsigned short* wp  = (unsigned short*)(wsb + WP_OFF);
  unsigned short* qb  = (unsigned short*)(wsb + QB_OFF);
  unsigned short* kb_ = (unsigned short*)(wsb + KB_OFF);
  unsigned short* vt  = (unsigned short*)(wsb + VT_OFF);
  unsigned short* aB  = (unsigned short*)(wsb + AB_OFF);

  prep_w<<<512, 256, 0, stream>>>(w_qkv, w_proj, wq, wp);
  prep_xT<<<dim3(16, 8, BB), 256, 0, stream>>>(x, xT);
  qkv_mfma<<<dim3(8, 12, BB), 256, 0, stream>>>(wq, xT, qb, kb_, vt);
  attn_mfma<<<dim3(BB * NH, NN / 256), 256, 0, stream>>>(qb, kb_, vt, aB);
  proj_mfma<<<dim3(8, 4, BB), 256, 0, stream>>>(wp, aB, b_proj, out);
}